// Round 6
// baseline (1913.410 us; speedup 1.0000x reference)
//
#include <hip/hip_runtime.h>
#include <math.h>
#include <stdint.h>

// ---------------------------------------------------------------------------
// GCN: 6 layers of  h' = act( segsum_dst( edge_val * (h @ W)[src] ) + b )
// dims: 512 -> 12 -> 10 -> 8 -> 6 -> 4 -> 7
//
// Round 9: persistent chain v2 = R6's PROVEN layer body (LDS ebuf staging +
// per-thread run-accumulation over ld-sorted edges + amortized flush) made
// persistent across all 6 layers. R5's chain failure causes each fixed:
//   - 66-node buckets -> NB=1516 <= 1536 = 6 blocks/CU x 256 CU co-resident
//     (24 waves/CU, same as R6 layers; R5 had 12)
//   - edges staged into LDS ONCE, persist across layers (R5 read strided
//     uncoalesced per-thread chunks from global every layer)
//   - __launch_bounds__(256,6) caps VGPR for guaranteed 6 blocks/CU
// Saves vs R6: 5x edge re-read (128 MB), 5x restaging, 5x launch/drain tails.
// R7/R8 lesson kept: staging + register run-accum is worth 5x; flush
// mechanics neutral. CSR: padded buckets (hist/scanC/scatter) + ld-sort
// finalize. 6 dispatches total.
// ---------------------------------------------------------------------------

#define T_EDGES 12800   // edges per tile (E=3.2M -> exactly 250 tiles)
#define NB_MAX  1600    // max fine buckets
#define BKT     66      // nodes per bucket (ceil(100000/66)=1516 <= 1536)
#define FCAP    2560    // edge slots per bucket (mean 2112, +9.7 sigma)
#define ASTR    13      // padded acc stride
#define ACCN    (BKT * ASTR)   // 858 floats

// ---- per-tile bucket histogram (+ grid-barrier counter init) ----
__global__ __launch_bounds__(512) void hist_kernel(const int* __restrict__ dst,
                                                   int* __restrict__ ghist,
                                                   int* __restrict__ gbar, int E, int NB) {
    __shared__ int h[NB_MAX];
    for (int i = threadIdx.x; i < NB; i += 512) h[i] = 0;
    if (blockIdx.x == 0 && threadIdx.x < 8) atomicExch(&gbar[threadIdx.x], 0);
    __syncthreads();
    int base = blockIdx.x * T_EDGES;
    int n = min(T_EDGES, E - base);
    for (int i = threadIdx.x; i < n; i += 512)
        atomicAdd(&h[(unsigned)dst[base + i] / BKT], 1);
    __syncthreads();
    for (int i = threadIdx.x; i < NB; i += 512)
        ghist[(size_t)blockIdx.x * NB + i] = h[i];
}

// ---- per-(tile,bucket) global offsets in padded layout + per-bucket totals ----
__global__ __launch_bounds__(256) void scanC_kernel(const int* __restrict__ ghist,
                                                    int* __restrict__ goff,
                                                    int* __restrict__ btot, int NT, int NB) {
    __shared__ int part[256];
    int b = blockIdx.x, t = threadIdx.x;
    int v = (t < NT) ? ghist[(size_t)t * NB + b] : 0;
    part[t] = v;
    __syncthreads();
    for (int off = 1; off < 256; off <<= 1) {
        int x = (t >= off) ? part[t - off] : 0;
        __syncthreads();
        part[t] += x;
        __syncthreads();
    }
    if (t < NT) goff[(size_t)t * NB + b] = b * FCAP + part[t] - v;
    if (t == 255) btot[b] = part[255];
}

// ---- scatter: LDS counting-sort per tile, run-writes to exact offsets ----
__global__ __launch_bounds__(1024) void scatter_kernel(const int* __restrict__ src,
                                                       const int* __restrict__ dst,
                                                       const float* __restrict__ val,
                                                       const int* __restrict__ ghist,
                                                       const int* __restrict__ goff,
                                                       int2* __restrict__ edges, int E, int NB) {
    __shared__ unsigned perm[T_EDGES];   // 51200 B
    __shared__ int loff[NB_MAX];         // 6400 B
    __shared__ int lcur[NB_MAX];         // 6400 B
    __shared__ int part[1024];           // 4096 B
    int tb = blockIdx.x, t = threadIdx.x;
    int base = tb * T_EDGES;
    int n = min(T_EDGES, E - base);

    int chunk = (NB + 1023) / 1024;
    int lo = t * chunk, hi = min(lo + chunk, NB);
    int s = 0;
    for (int i = lo; i < hi; i++) {
        int c = ghist[(size_t)tb * NB + i];
        loff[i] = c;
        s += c;
    }
    part[t] = s;
    __syncthreads();
    for (int off = 1; off < 1024; off <<= 1) {
        int x = (t >= off) ? part[t - off] : 0;
        __syncthreads();
        part[t] += x;
        __syncthreads();
    }
    int run = part[t] - s;
    for (int i = lo; i < hi; i++) {
        int c = loff[i];
        loff[i] = run;
        lcur[i] = run;
        run += c;
    }
    __syncthreads();

    // rank: perm = local_idx | bucket<<14 | localdst<<25  (14+11+7 = 32 bits)
    for (int i = t; i < n; i += 1024) {
        int d = dst[base + i];
        unsigned b = (unsigned)d / BKT;
        unsigned ld = (unsigned)d - b * BKT;
        int p = atomicAdd(&lcur[b], 1);
        perm[p] = (unsigned)i | (b << 14) | (ld << 25);
    }
    __syncthreads();

    for (int o = t; o < n; o += 1024) {
        unsigned v = perm[o];
        int li = v & 16383;
        int b  = (v >> 14) & 2047;
        int ld = v >> 25;
        int g  = goff[(size_t)tb * NB + b] + (o - loff[b]);
        edges[g] = make_int2(src[base + li] | (ld << 17), __float_as_int(val[base + li]));
    }
}

// ---- finalize: per-bucket LDS reorder, sort by local dst (enables run-accum) ----
__global__ __launch_bounds__(512) void finalize_kernel(int2* __restrict__ edges,
                                                       const int* __restrict__ btot) {
    __shared__ int2 recs[FCAP];
    __shared__ int2 recs2[FCAP];
    __shared__ int cnt[BKT], offs[BKT], cur[BKT];
    int b = blockIdx.x, t = threadIdx.x;
    size_t s0 = (size_t)b * FCAP;
    int ne = min(btot[b], FCAP);
    if (t < BKT) cnt[t] = 0;
    __syncthreads();
    for (int i = t; i < ne; i += 512) {
        int2 r = edges[s0 + i];
        recs[i] = r;
        atomicAdd(&cnt[(r.x >> 17) & 127], 1);
    }
    __syncthreads();
    if (t == 0) {
        int run = 0;
        for (int i = 0; i < BKT; i++) { offs[i] = run; run += cnt[i]; }
    }
    __syncthreads();
    if (t < BKT) cur[t] = offs[t];
    __syncthreads();
    for (int i = t; i < ne; i += 512) {
        int2 r = recs[i];
        int ld = (r.x >> 17) & 127;
        int p = atomicAdd(&cur[ld], 1);
        recs2[p] = r;
    }
    __syncthreads();
    for (int i = t; i < ne; i += 512) edges[s0 + i] = recs2[i];  // coalesced
}

// ---- layer 1 dense: s1 = x @ W1, out stride 16 (64 B rows, pads zeroed) ----
__global__ __launch_bounds__(256) void dense1_kernel(const float* __restrict__ x,
                                                     const float* __restrict__ W,
                                                     float* __restrict__ out, int N) {
    __shared__ float xs[256 * 33];
    const int t    = threadIdx.x;
    const int row0 = blockIdx.x * 256;
    const int r    = row0 + t;

    float acc[12];
#pragma unroll
    for (int j = 0; j < 12; j++) acc[j] = 0.f;

    for (int tile = 0; tile < 16; ++tile) {
#pragma unroll
        for (int i = 0; i < 8; i++) {
            int idx4 = t + 256 * i;
            int flat = idx4 * 4;
            int rl   = flat >> 5;
            int c    = flat & 31;
            int rg   = row0 + rl;
            if (rg >= N) rg = N - 1;
            const float4 v = *(const float4*)(x + (size_t)rg * 512 + tile * 32 + c);
            float* p = &xs[rl * 33 + c];
            p[0] = v.x; p[1] = v.y; p[2] = v.z; p[3] = v.w;
        }
        __syncthreads();
#pragma unroll 8
        for (int kk = 0; kk < 32; ++kk) {
            float xv = xs[t * 33 + kk];
            int k = tile * 32 + kk;
#pragma unroll
            for (int j = 0; j < 12; j++) acc[j] += xv * W[k * 12 + j];
        }
        __syncthreads();
    }
    if (r < N) {
        float4* orow = (float4*)(out + (size_t)r * 16);
        orow[0] = make_float4(acc[0], acc[1], acc[2], acc[3]);
        orow[1] = make_float4(acc[4], acc[5], acc[6], acc[7]);
        orow[2] = make_float4(acc[8], acc[9], acc[10], acc[11]);
        orow[3] = make_float4(0.f, 0.f, 0.f, 0.f);
    }
}

// ---- device-scope grid barrier (all NB blocks co-resident by construction) ----
__device__ __forceinline__ void gsync(int* ctr, int nblk) {
    __syncthreads();
    if (threadIdx.x == 0) {
        __threadfence();                      // release
        atomicAdd(ctr, 1);                    // device-scope arrive
        int spins = 0;
        while (__hip_atomic_load(ctr, __ATOMIC_RELAXED, __HIP_MEMORY_SCOPE_AGENT) < nblk) {
            __builtin_amdgcn_s_sleep(8);
            if (++spins > (1 << 20)) break;   // fail visibly, never hang
        }
    }
    __syncthreads();
    __threadfence();                          // acquire
}

// ---- R6's proven layer body: run-accumulate over ld-sorted resident ebuf ----
// SV: float4-stride of input rows. NACC: float4s accumulated (<=SV).
// ACT: 0 none, 1 relu, 2 tanhshrink.  FINAL: write h as DIN floats.
template <int SV, int NACC, int DIN, int DOUT, int OSTR, int ACT, bool FINAL>
__device__ __forceinline__ void layer_body(int b, int ne, const int2* ebuf, float* acc,
                                           const float* __restrict__ s,
                                           const float* __restrict__ bias,
                                           const float* __restrict__ W,
                                           float* __restrict__ out, int N) {
    const int t = threadIdx.x;
    for (int i = t; i < ACCN; i += 256) acc[i] = 0.f;
    __syncthreads();

    const int K  = (ne + 255) >> 8;          // <= 10
    const int i0 = t * K;
    const int i1 = min(i0 + K, ne);
    if (i0 < i1) {
        const float4* sv = (const float4*)s;
        float4 a[NACC];
#pragma unroll
        for (int v = 0; v < NACC; v++) a[v] = make_float4(0.f, 0.f, 0.f, 0.f);
        int cd = (ebuf[i0].x >> 17) & 127;
        for (int i = i0; i < i1; ++i) {
            int2 ev = ebuf[i];
            int ld = (ev.x >> 17) & 127;
            if (ld != cd) {
#pragma unroll
                for (int v = 0; v < NACC; v++) {
                    atomicAdd(&acc[cd * ASTR + 4 * v + 0], a[v].x);
                    atomicAdd(&acc[cd * ASTR + 4 * v + 1], a[v].y);
                    atomicAdd(&acc[cd * ASTR + 4 * v + 2], a[v].z);
                    atomicAdd(&acc[cd * ASTR + 4 * v + 3], a[v].w);
                    a[v] = make_float4(0.f, 0.f, 0.f, 0.f);
                }
                cd = ld;
            }
            float w = __int_as_float(ev.y);
            const float4* srow = sv + (size_t)(ev.x & 0x1FFFF) * SV;
#pragma unroll
            for (int v = 0; v < NACC; v++) {
                float4 xr = srow[v];
                a[v].x += w * xr.x; a[v].y += w * xr.y;
                a[v].z += w * xr.z; a[v].w += w * xr.w;
            }
        }
#pragma unroll
        for (int v = 0; v < NACC; v++) {
            atomicAdd(&acc[cd * ASTR + 4 * v + 0], a[v].x);
            atomicAdd(&acc[cd * ASTR + 4 * v + 1], a[v].y);
            atomicAdd(&acc[cd * ASTR + 4 * v + 2], a[v].z);
            atomicAdd(&acc[cd * ASTR + 4 * v + 3], a[v].w);
        }
    }
    __syncthreads();

    // epilogue: node-per-thread (t<BKT), bias+act, next dense, coalesced store
    if (t < BKT) {
        int node = b * BKT + t;
        if (node < N) {
            float h[DIN];
#pragma unroll
            for (int k = 0; k < DIN; k++) {
                float z = acc[t * ASTR + k] + bias[k];
                if (ACT == 1) z = fmaxf(z, 0.f);
                else if (ACT == 2) z = z - tanhf(z);
                h[k] = z;
            }
            if (FINAL) {
#pragma unroll
                for (int k = 0; k < DIN; k++) out[(size_t)node * DIN + k] = h[k];
            } else {
                float o[OSTR];
#pragma unroll
                for (int j = 0; j < OSTR; j++) o[j] = 0.f;  // zero pads
#pragma unroll
                for (int j = 0; j < DOUT; j++) {
                    float tj = 0.f;
#pragma unroll
                    for (int k = 0; k < DIN; k++) tj += h[k] * W[k * DOUT + j];
                    o[j] = tj;
                }
                float4* orow = (float4*)(out + (size_t)node * OSTR);
#pragma unroll
                for (int v = 0; v < OSTR / 4; v++)
                    orow[v] = make_float4(o[4 * v], o[4 * v + 1], o[4 * v + 2], o[4 * v + 3]);
            }
        }
    }
    __syncthreads();   // protect acc/ebuf before next layer
}

// ---- the whole 6-layer gather chain, one persistent co-resident kernel ----
// grid = NB (<=1536); 23.9 KB LDS -> 6 blocks/CU -> all blocks co-resident.
__global__ __launch_bounds__(256, 6) void chain_kernel(
    const int2* __restrict__ edges, const int* __restrict__ btot,
    float* __restrict__ A, float* __restrict__ B,
    const float* __restrict__ b1, const float* __restrict__ W2,
    const float* __restrict__ b2, const float* __restrict__ W3,
    const float* __restrict__ b3, const float* __restrict__ W4,
    const float* __restrict__ b4, const float* __restrict__ W5,
    const float* __restrict__ b5, const float* __restrict__ W6,
    const float* __restrict__ b6, float* __restrict__ out,
    int N, int* __restrict__ gbar) {
    __shared__ int2  ebuf[FCAP];          // 20480 B -- persists across layers
    __shared__ float acc[ACCN];           // 3432 B
    const int b = blockIdx.x, t = threadIdx.x;
    const int ne = min(btot[b], FCAP);
    const int g = gridDim.x;

    // stage this bucket's sorted edges ONCE (coalesced); reused by all 6 layers
    for (int i = t; i < ne; i += 256) ebuf[i] = edges[(size_t)b * FCAP + i];
    // (no barrier needed: layer_body syncs after acc-zero before reading ebuf)

    layer_body<4, 3, 12, 10, 16, 0, false>(b, ne, ebuf, acc, A, b1, W2, B, N);
    gsync(&gbar[0], g);
    layer_body<4, 3, 10,  8,  8, 1, false>(b, ne, ebuf, acc, B, b2, W3, A, N);
    gsync(&gbar[1], g);
    layer_body<2, 2,  8,  6,  8, 2, false>(b, ne, ebuf, acc, A, b3, W4, B, N);
    gsync(&gbar[2], g);
    layer_body<2, 2,  6,  4,  4, 2, false>(b, ne, ebuf, acc, B, b4, W5, A, N);
    gsync(&gbar[3], g);
    layer_body<1, 1,  4,  7,  8, 0, false>(b, ne, ebuf, acc, A, b5, W6, B, N);
    gsync(&gbar[4], g);
    layer_body<2, 2,  7,  7,  8, 0, true >(b, ne, ebuf, acc, B, b6, (const float*)nullptr, out, N);
}

// ---------------- launcher ----------------

static inline size_t align256(size_t x) { return (x + 255) & ~(size_t)255; }

extern "C" void kernel_launch(void* const* d_in, const int* in_sizes, int n_in,
                              void* d_out, int out_size, void* d_ws, size_t ws_size,
                              hipStream_t stream) {
    const float* x        = (const float*)d_in[0];
    const float* edge_val = (const float*)d_in[1];
    const int*   edge_src = (const int*)d_in[2];
    const int*   edge_dst = (const int*)d_in[3];
    const float* W1 = (const float*)d_in[4];   const float* b1 = (const float*)d_in[5];
    const float* W2 = (const float*)d_in[6];   const float* b2 = (const float*)d_in[7];
    const float* W3 = (const float*)d_in[8];   const float* b3 = (const float*)d_in[9];
    const float* W4 = (const float*)d_in[10];  const float* b4 = (const float*)d_in[11];
    const float* W5 = (const float*)d_in[12];  const float* b5 = (const float*)d_in[13];
    const float* W6 = (const float*)d_in[14];  const float* b6 = (const float*)d_in[15];

    const int N = in_sizes[0] / 512;        // 100000
    const int E = in_sizes[1];              // 3200000
    float* out = (float*)d_out;

    const int NB = (N + BKT - 1) / BKT;     // 1516 buckets (<= 1536 co-resident)
    const int NT = (E + T_EDGES - 1) / T_EDGES;  // 250 tiles (<=256 required)
    const int nb = (N + 255) / 256;

    // workspace carve-up (~47 MB)
    char* w = (char*)d_ws;
    float* A     = (float*)w;  w += align256((size_t)N * 16 * sizeof(float));
    float* B     = (float*)w;  w += align256((size_t)N * 16 * sizeof(float));
    int*   ghist = (int*)w;    w += align256((size_t)NT * NB * sizeof(int));
    int*   goff  = (int*)w;    w += align256((size_t)NT * NB * sizeof(int));
    int*   btot  = (int*)w;    w += align256((size_t)NB * sizeof(int));
    int*   gbar  = (int*)w;    w += align256(32 * sizeof(int));
    int2*  edges = (int2*)w;   w += align256((size_t)NB * FCAP * sizeof(int2));

    // ---- CSR build: radix partition into strided padded buckets + ld-sort ----
    hist_kernel<<<NT, 512, 0, stream>>>(edge_dst, ghist, gbar, E, NB);
    scanC_kernel<<<NB, 256, 0, stream>>>(ghist, goff, btot, NT, NB);
    scatter_kernel<<<NT, 1024, 0, stream>>>(edge_src, edge_dst, edge_val, ghist, goff, edges, E, NB);
    finalize_kernel<<<NB, 512, 0, stream>>>(edges, btot);

    // ---- dense1: s1 = x @ W1 (stride 16, 64 B-aligned rows) ----
    dense1_kernel<<<nb, 256, 0, stream>>>(x, W1, A, N);

    // ---- all 6 gather layers: one persistent co-resident kernel ----
    chain_kernel<<<NB, 256, 0, stream>>>(edges, btot, A, B, b1, W2, b2, W3, b3, W4,
                                         b4, W5, b5, W6, b6, out, N, gbar);
}

// Round 7
// 706.037 us; speedup vs baseline: 2.7101x; 2.7101x over previous
//
#include <hip/hip_runtime.h>
#include <math.h>
#include <stdint.h>

// ---------------------------------------------------------------------------
// GCN: 6 layers of  h' = act( segsum_dst( edge_val * (h @ W)[src] ) + b )
// dims: 512 -> 12 -> 10 -> 8 -> 6 -> 4 -> 7
//
// Round 10: R6's proven separate-dispatch structure + serial-overhead trims.
// Persistent chains are dead (R5: occupancy+coalescing; R9: acquire-fence L2
// invalidation -> HBM-latency gathers, 170 GB/s). Layers are ~85% of their
// gather line-traffic roofline (205 MB L2/L3 lines per layer) - untouched.
// Trims:
//  - hist fused into dense1 dispatch (role-split blocks; hist's ~10us hides
//    under dense1's 204 MB stream), -1 launch
//  - padded bucket layout (base=b*FCAP, R7-verified): scanA/scanB deleted
//  - finalize at 1024 threads (41.7 KB LDS -> 32 waves/CU vs 24)
// 10 dispatches total.
// ---------------------------------------------------------------------------

#define T_EDGES 12800   // edges per tile (E=3.2M -> exactly 250 tiles)
#define NB_MAX  1600    // max fine buckets (N<=102400)
#define FCAP    2560    // edge slots per 64-node bucket (mean 2048, max~2202)

// ---- fused: per-tile bucket histogram (blocks 0..NT-1) + dense1 (rest) ----
// dense1: s1 = x @ W1, out stride 16 (64 B rows, pads zeroed)
__global__ __launch_bounds__(256) void hist_dense1_kernel(const int* __restrict__ dst,
                                                          int* __restrict__ ghist,
                                                          const float* __restrict__ x,
                                                          const float* __restrict__ W,
                                                          float* __restrict__ out,
                                                          int E, int NB, int NT, int N) {
    __shared__ __align__(16) char smem[256 * 33 * 4];   // union: hist h[] / dense1 xs[]
    const int t = threadIdx.x;

    if (blockIdx.x < NT) {
        // ---------------- hist role ----------------
        int* h = (int*)smem;
        for (int i = t; i < NB; i += 256) h[i] = 0;
        __syncthreads();
        int base = blockIdx.x * T_EDGES;
        int n = min(T_EDGES, E - base);
        for (int i = t; i < n; i += 256)
            atomicAdd(&h[((unsigned)dst[base + i]) >> 6], 1);
        __syncthreads();
        for (int i = t; i < NB; i += 256)
            ghist[(size_t)blockIdx.x * NB + i] = h[i];
        return;
    }

    // ---------------- dense1 role ----------------
    float* xs = (float*)smem;
    const int row0 = (blockIdx.x - NT) * 256;
    const int r    = row0 + t;

    float acc[12];
#pragma unroll
    for (int j = 0; j < 12; j++) acc[j] = 0.f;

    for (int tile = 0; tile < 16; ++tile) {
#pragma unroll
        for (int i = 0; i < 8; i++) {
            int idx4 = t + 256 * i;
            int flat = idx4 * 4;
            int rl   = flat >> 5;
            int c    = flat & 31;
            int rg   = row0 + rl;
            if (rg >= N) rg = N - 1;
            const float4 v = *(const float4*)(x + (size_t)rg * 512 + tile * 32 + c);
            float* p = &xs[rl * 33 + c];
            p[0] = v.x; p[1] = v.y; p[2] = v.z; p[3] = v.w;
        }
        __syncthreads();
#pragma unroll 8
        for (int kk = 0; kk < 32; ++kk) {
            float xv = xs[t * 33 + kk];
            int k = tile * 32 + kk;
#pragma unroll
            for (int j = 0; j < 12; j++) acc[j] += xv * W[k * 12 + j];
        }
        __syncthreads();
    }
    if (r < N) {
        float4* orow = (float4*)(out + (size_t)r * 16);
        orow[0] = make_float4(acc[0], acc[1], acc[2], acc[3]);
        orow[1] = make_float4(acc[4], acc[5], acc[6], acc[7]);
        orow[2] = make_float4(acc[8], acc[9], acc[10], acc[11]);
        orow[3] = make_float4(0.f, 0.f, 0.f, 0.f);
    }
}

// ---- per-(tile,bucket) global offsets in padded layout + per-bucket totals ----
__global__ __launch_bounds__(256) void scanC_kernel(const int* __restrict__ ghist,
                                                    int* __restrict__ goff,
                                                    int* __restrict__ btot, int NT, int NB) {
    __shared__ int part[256];
    int b = blockIdx.x, t = threadIdx.x;
    int v = (t < NT) ? ghist[(size_t)t * NB + b] : 0;
    part[t] = v;
    __syncthreads();
    for (int off = 1; off < 256; off <<= 1) {
        int x = (t >= off) ? part[t - off] : 0;
        __syncthreads();
        part[t] += x;
        __syncthreads();
    }
    if (t < NT) goff[(size_t)t * NB + b] = b * FCAP + part[t] - v;
    if (t == 255) btot[b] = part[255];
}

// ---- scatter: LDS counting-sort per tile, run-writes to exact offsets ----
__global__ __launch_bounds__(1024) void scatter_kernel(const int* __restrict__ src,
                                                       const int* __restrict__ dst,
                                                       const float* __restrict__ val,
                                                       const int* __restrict__ ghist,
                                                       const int* __restrict__ goff,
                                                       int2* __restrict__ edges, int E, int NB) {
    __shared__ unsigned perm[T_EDGES];   // 51200 B
    __shared__ int loff[NB_MAX];         // 6400 B
    __shared__ int lcur[NB_MAX];         // 6400 B
    __shared__ int part[1024];           // 4096 B
    int tb = blockIdx.x, t = threadIdx.x;
    int base = tb * T_EDGES;
    int n = min(T_EDGES, E - base);

    int chunk = (NB + 1023) / 1024;
    int lo = t * chunk, hi = min(lo + chunk, NB);
    int s = 0;
    for (int i = lo; i < hi; i++) {
        int c = ghist[(size_t)tb * NB + i];
        loff[i] = c;
        s += c;
    }
    part[t] = s;
    __syncthreads();
    for (int off = 1; off < 1024; off <<= 1) {
        int x = (t >= off) ? part[t - off] : 0;
        __syncthreads();
        part[t] += x;
        __syncthreads();
    }
    int run = part[t] - s;
    for (int i = lo; i < hi; i++) {
        int c = loff[i];
        loff[i] = run;
        lcur[i] = run;
        run += c;
    }
    __syncthreads();

    // rank: perm = local_idx | bucket<<14 | localdst<<25
    for (int i = t; i < n; i += 1024) {
        int d = dst[base + i];
        unsigned b = ((unsigned)d) >> 6;
        int p = atomicAdd(&lcur[b], 1);
        perm[p] = (unsigned)i | (b << 14) | ((unsigned)(d & 63) << 25);
    }
    __syncthreads();

    for (int o = t; o < n; o += 1024) {
        unsigned v = perm[o];
        int li = v & 16383;
        int b  = (v >> 14) & 2047;
        int ld = v >> 25;
        int g  = goff[(size_t)tb * NB + b] + (o - loff[b]);
        edges[g] = make_int2(src[base + li] | (ld << 17), __float_as_int(val[base + li]));
    }
}

// ---- finalize: per-bucket LDS reorder, sort by local dst (enables run-accum) ----
// 1024 threads: 41.7 KB LDS -> 2 blocks/CU x 16 waves = 32 waves/CU (vs 24 @512)
__global__ __launch_bounds__(1024) void finalize_kernel(int2* __restrict__ edges,
                                                        const int* __restrict__ btot) {
    __shared__ int2 recs[FCAP];          // 20480 B
    __shared__ int2 recs2[FCAP];         // 20480 B
    __shared__ int cnt[64], offs[64], cur[64];
    int b = blockIdx.x, t = threadIdx.x;
    size_t s0 = (size_t)b * FCAP;
    int ne = min(btot[b], FCAP);
    if (t < 64) cnt[t] = 0;
    __syncthreads();
    for (int i = t; i < ne; i += 1024) {
        int2 r = edges[s0 + i];
        recs[i] = r;
        atomicAdd(&cnt[(r.x >> 17) & 63], 1);
    }
    __syncthreads();
    if (t == 0) {
        int run = 0;
        for (int i = 0; i < 64; i++) { offs[i] = run; run += cnt[i]; }
    }
    __syncthreads();
    if (t < 64) cur[t] = offs[t];
    __syncthreads();
    for (int i = t; i < ne; i += 1024) {
        int2 r = recs[i];
        int ld = (r.x >> 17) & 63;
        int p = atomicAdd(&cur[ld], 1);
        recs2[p] = r;                         // keep ld packed for gather
    }
    __syncthreads();
    for (int i = t; i < ne; i += 1024) edges[s0 + i] = recs2[i];  // coalesced
}

// ---- bucket-parallel fused layer (R6's proven body, padded-layout addressing):
//   agg_k (staged ebuf, run-accumulated) + h=act(agg+b_k) + s_{k+1}=h@W_{k+1}
// SV: float4-stride of input rows. NACC: float4s accumulated (<=SV).
// ACT: 0 none, 1 relu, 2 tanhshrink.  FINAL: write h as DIN floats.
template <int SV, int NACC, int DIN, int DOUT, int OSTR, int ACT, bool FINAL>
__global__ __launch_bounds__(256) void layer_kernel(const int2* __restrict__ edges,
                                                    const int* __restrict__ btot,
                                                    const float* __restrict__ s,
                                                    const float* __restrict__ bias,
                                                    const float* __restrict__ W,
                                                    float* __restrict__ out, int N) {
    constexpr int ASTR = 13;                 // padded acc stride (conflict-free)
    __shared__ int2  ebuf[FCAP];             // 20480 B
    __shared__ float acc[64 * ASTR];         // 3328 B
    const int b = blockIdx.x, t = threadIdx.x;
    const int ne = min(btot[b], FCAP);

    for (int i = t; i < 64 * ASTR; i += 256) acc[i] = 0.f;
    for (int i = t; i < ne; i += 256) ebuf[i] = edges[(size_t)b * FCAP + i];  // coalesced stage
    __syncthreads();

    // per-thread contiguous chunk of sorted edges; run-accumulate in registers
    const int K  = (ne + 255) >> 8;          // <= 10
    const int i0 = t * K;
    const int i1 = min(i0 + K, ne);
    if (i0 < i1) {
        const float4* sv = (const float4*)s;
        float4 a[NACC];
#pragma unroll
        for (int v = 0; v < NACC; v++) a[v] = make_float4(0.f, 0.f, 0.f, 0.f);
        int cd = (ebuf[i0].x >> 17) & 63;
        for (int i = i0; i < i1; ++i) {
            int2 ev = ebuf[i];
            int ld = (ev.x >> 17) & 63;
            if (ld != cd) {
#pragma unroll
                for (int v = 0; v < NACC; v++) {
                    atomicAdd(&acc[cd * ASTR + 4 * v + 0], a[v].x);
                    atomicAdd(&acc[cd * ASTR + 4 * v + 1], a[v].y);
                    atomicAdd(&acc[cd * ASTR + 4 * v + 2], a[v].z);
                    atomicAdd(&acc[cd * ASTR + 4 * v + 3], a[v].w);
                    a[v] = make_float4(0.f, 0.f, 0.f, 0.f);
                }
                cd = ld;
            }
            float w = __int_as_float(ev.y);
            const float4* srow = sv + (size_t)(ev.x & 0x1FFFF) * SV;
#pragma unroll
            for (int v = 0; v < NACC; v++) {
                float4 xr = srow[v];
                a[v].x += w * xr.x; a[v].y += w * xr.y;
                a[v].z += w * xr.z; a[v].w += w * xr.w;
            }
        }
#pragma unroll
        for (int v = 0; v < NACC; v++) {
            atomicAdd(&acc[cd * ASTR + 4 * v + 0], a[v].x);
            atomicAdd(&acc[cd * ASTR + 4 * v + 1], a[v].y);
            atomicAdd(&acc[cd * ASTR + 4 * v + 2], a[v].z);
            atomicAdd(&acc[cd * ASTR + 4 * v + 3], a[v].w);
        }
    }
    __syncthreads();

    // epilogue: node-per-thread (t<64), bias+act, next dense, coalesced store
    if (t < 64) {
        int node = (b << 6) + t;
        if (node < N) {
            float h[DIN];
#pragma unroll
            for (int k = 0; k < DIN; k++) {
                float z = acc[t * ASTR + k] + bias[k];
                if (ACT == 1) z = fmaxf(z, 0.f);
                else if (ACT == 2) z = z - tanhf(z);
                h[k] = z;
            }
            if (FINAL) {
#pragma unroll
                for (int k = 0; k < DIN; k++) out[(size_t)node * DIN + k] = h[k];
            } else {
                float o[OSTR];
#pragma unroll
                for (int j = 0; j < OSTR; j++) o[j] = 0.f;  // zero pads
#pragma unroll
                for (int j = 0; j < DOUT; j++) {
                    float tj = 0.f;
#pragma unroll
                    for (int k = 0; k < DIN; k++) tj += h[k] * W[k * DOUT + j];
                    o[j] = tj;
                }
                float4* orow = (float4*)(out + (size_t)node * OSTR);
#pragma unroll
                for (int v = 0; v < OSTR / 4; v++)
                    orow[v] = make_float4(o[4 * v], o[4 * v + 1], o[4 * v + 2], o[4 * v + 3]);
            }
        }
    }
}

// ---------------- launcher ----------------

static inline size_t align256(size_t x) { return (x + 255) & ~(size_t)255; }

extern "C" void kernel_launch(void* const* d_in, const int* in_sizes, int n_in,
                              void* d_out, int out_size, void* d_ws, size_t ws_size,
                              hipStream_t stream) {
    const float* x        = (const float*)d_in[0];
    const float* edge_val = (const float*)d_in[1];
    const int*   edge_src = (const int*)d_in[2];
    const int*   edge_dst = (const int*)d_in[3];
    const float* W1 = (const float*)d_in[4];   const float* b1 = (const float*)d_in[5];
    const float* W2 = (const float*)d_in[6];   const float* b2 = (const float*)d_in[7];
    const float* W3 = (const float*)d_in[8];   const float* b3 = (const float*)d_in[9];
    const float* W4 = (const float*)d_in[10];  const float* b4 = (const float*)d_in[11];
    const float* W5 = (const float*)d_in[12];  const float* b5 = (const float*)d_in[13];
    const float* W6 = (const float*)d_in[14];  const float* b6 = (const float*)d_in[15];

    const int N = in_sizes[0] / 512;        // 100000
    const int E = in_sizes[1];              // 3200000
    float* out = (float*)d_out;

    const int NB = (N + 63) >> 6;           // 1563 fine buckets
    const int NT = (E + T_EDGES - 1) / T_EDGES;  // 250 tiles (<=256 required)
    const int nb = (N + 255) / 256;         // 391 dense1 blocks

    // workspace carve-up (~60 MB)
    char* w = (char*)d_ws;
    float* A     = (float*)w;  w += align256((size_t)N * 16 * sizeof(float));
    float* B     = (float*)w;  w += align256((size_t)N * 16 * sizeof(float));
    int*   ghist = (int*)w;    w += align256((size_t)NT * NB * sizeof(int));
    int*   goff  = (int*)w;    w += align256((size_t)NT * NB * sizeof(int));
    int*   btot  = (int*)w;    w += align256((size_t)NB * sizeof(int));
    int2*  edges = (int2*)w;   w += align256((size_t)NB * FCAP * sizeof(int2));

    // ---- fused hist + dense1 (hist hides under dense1's 204 MB stream) ----
    hist_dense1_kernel<<<NT + nb, 256, 0, stream>>>(edge_dst, ghist, x, W1, A, E, NB, NT, N);

    // ---- CSR build: padded bucket layout + ld-sort ----
    scanC_kernel<<<NB, 256, 0, stream>>>(ghist, goff, btot, NT, NB);
    scatter_kernel<<<NT, 1024, 0, stream>>>(edge_src, edge_dst, edge_val, ghist, goff, edges, E, NB);
    finalize_kernel<<<NB, 1024, 0, stream>>>(edges, btot);

    // ---- fused bucket-parallel gather+dense chain (R6 bodies) ----
    // G1: agg(s1,str16) -> h1=agg+b1 -> s2=h1@W2 (12->10, out stride 16)
    layer_kernel<4, 3, 12, 10, 16, 0, false><<<NB, 256, 0, stream>>>(edges, btot, A, b1, W2, B, N);
    // G2: agg(s2,str16) -> h2=relu -> s3=h2@W3 (10->8, out stride 8)
    layer_kernel<4, 3, 10, 8, 8, 1, false><<<NB, 256, 0, stream>>>(edges, btot, B, b2, W3, A, N);
    // G3: agg(s3,str8) -> h3=ts -> s4=h3@W4 (8->6, out stride 8)
    layer_kernel<2, 2, 8, 6, 8, 2, false><<<NB, 256, 0, stream>>>(edges, btot, A, b3, W4, B, N);
    // G4: agg(s4,str8) -> h4=ts -> s5=h4@W5 (6->4, out stride 4)
    layer_kernel<2, 2, 6, 4, 4, 2, false><<<NB, 256, 0, stream>>>(edges, btot, B, b4, W5, A, N);
    // G5: agg(s5,str4) -> h5=agg+b5 -> s6=h5@W6 (4->7, out stride 8)
    layer_kernel<1, 1, 4, 7, 8, 0, false><<<NB, 256, 0, stream>>>(edges, btot, A, b5, W6, B, N);
    // G6: out = agg6 + b6 (7 floats, exact layout)
    layer_kernel<2, 2, 7, 7, 8, 0, true><<<NB, 256, 0, stream>>>(edges, btot, B, b6, (const float*)nullptr, out, N);
}

// Round 8
// 699.850 us; speedup vs baseline: 2.7340x; 1.0088x over previous
//
#include <hip/hip_runtime.h>
#include <math.h>
#include <stdint.h>

// ---------------------------------------------------------------------------
// GCN: 6 layers of  h' = act( segsum_dst( edge_val * (h @ W)[src] ) + b )
// dims: 512 -> 12 -> 10 -> 8 -> 6 -> 4 -> 7
//
// Round 11: R10 structure + scatter occupancy fix.
//  - T_EDGES 12800 -> 6400: scatter LDS 68 KB -> 42.4 KB = 2 blocks/CU,
//    grid 250 -> 500 blocks (two generations, 32 waves/CU in scatter;
//    was 1 block/CU, single generation, 16 waves/CU).
//  - scanC widened to 512 threads (NT=500 tiles <= 512).
//  - layer ebuf staging via int4 (2 edges per lane-op, bounded by ne).
// Layers/finalize/hist+dense1 identical to R10 (706.0 us verified).
// Persistent chains remain dead (R5/R9, two independent mechanisms).
// ---------------------------------------------------------------------------

#define T_EDGES 6400    // edges per tile (E=3.2M -> exactly 500 tiles)
#define NB_MAX  1600    // max fine buckets (N<=102400)
#define FCAP    2560    // edge slots per 64-node bucket (mean 2048, max~2202)

// ---- fused: per-tile bucket histogram (blocks 0..NT-1) + dense1 (rest) ----
// dense1: s1 = x @ W1, out stride 16 (64 B rows, pads zeroed)
__global__ __launch_bounds__(256) void hist_dense1_kernel(const int* __restrict__ dst,
                                                          int* __restrict__ ghist,
                                                          const float* __restrict__ x,
                                                          const float* __restrict__ W,
                                                          float* __restrict__ out,
                                                          int E, int NB, int NT, int N) {
    __shared__ __align__(16) char smem[256 * 33 * 4];   // union: hist h[] / dense1 xs[]
    const int t = threadIdx.x;

    if (blockIdx.x < NT) {
        // ---------------- hist role ----------------
        int* h = (int*)smem;
        for (int i = t; i < NB; i += 256) h[i] = 0;
        __syncthreads();
        int base = blockIdx.x * T_EDGES;
        int n = min(T_EDGES, E - base);
        for (int i = t; i < n; i += 256)
            atomicAdd(&h[((unsigned)dst[base + i]) >> 6], 1);
        __syncthreads();
        for (int i = t; i < NB; i += 256)
            ghist[(size_t)blockIdx.x * NB + i] = h[i];
        return;
    }

    // ---------------- dense1 role ----------------
    float* xs = (float*)smem;
    const int row0 = (blockIdx.x - NT) * 256;
    const int r    = row0 + t;

    float acc[12];
#pragma unroll
    for (int j = 0; j < 12; j++) acc[j] = 0.f;

    for (int tile = 0; tile < 16; ++tile) {
#pragma unroll
        for (int i = 0; i < 8; i++) {
            int idx4 = t + 256 * i;
            int flat = idx4 * 4;
            int rl   = flat >> 5;
            int c    = flat & 31;
            int rg   = row0 + rl;
            if (rg >= N) rg = N - 1;
            const float4 v = *(const float4*)(x + (size_t)rg * 512 + tile * 32 + c);
            float* p = &xs[rl * 33 + c];
            p[0] = v.x; p[1] = v.y; p[2] = v.z; p[3] = v.w;
        }
        __syncthreads();
#pragma unroll 8
        for (int kk = 0; kk < 32; ++kk) {
            float xv = xs[t * 33 + kk];
            int k = tile * 32 + kk;
#pragma unroll
            for (int j = 0; j < 12; j++) acc[j] += xv * W[k * 12 + j];
        }
        __syncthreads();
    }
    if (r < N) {
        float4* orow = (float4*)(out + (size_t)r * 16);
        orow[0] = make_float4(acc[0], acc[1], acc[2], acc[3]);
        orow[1] = make_float4(acc[4], acc[5], acc[6], acc[7]);
        orow[2] = make_float4(acc[8], acc[9], acc[10], acc[11]);
        orow[3] = make_float4(0.f, 0.f, 0.f, 0.f);
    }
}

// ---- per-(tile,bucket) global offsets in padded layout + per-bucket totals ----
// 512 threads: scans NT=500 tile entries per bucket.
__global__ __launch_bounds__(512) void scanC_kernel(const int* __restrict__ ghist,
                                                    int* __restrict__ goff,
                                                    int* __restrict__ btot, int NT, int NB) {
    __shared__ int part[512];
    int b = blockIdx.x, t = threadIdx.x;
    int v = (t < NT) ? ghist[(size_t)t * NB + b] : 0;
    part[t] = v;
    __syncthreads();
    for (int off = 1; off < 512; off <<= 1) {
        int x = (t >= off) ? part[t - off] : 0;
        __syncthreads();
        part[t] += x;
        __syncthreads();
    }
    if (t < NT) goff[(size_t)t * NB + b] = b * FCAP + part[t] - v;
    if (t == 511) btot[b] = part[511];
}

// ---- scatter: LDS counting-sort per tile, run-writes to exact offsets ----
// 42.4 KB LDS -> 2 blocks/CU (32 waves/CU); 500 blocks = 2 generations.
__global__ __launch_bounds__(1024) void scatter_kernel(const int* __restrict__ src,
                                                       const int* __restrict__ dst,
                                                       const float* __restrict__ val,
                                                       const int* __restrict__ ghist,
                                                       const int* __restrict__ goff,
                                                       int2* __restrict__ edges, int E, int NB) {
    __shared__ unsigned perm[T_EDGES];   // 25600 B
    __shared__ int loff[NB_MAX];         // 6400 B
    __shared__ int lcur[NB_MAX];         // 6400 B
    __shared__ int part[1024];           // 4096 B  (total 42496 B)
    int tb = blockIdx.x, t = threadIdx.x;
    int base = tb * T_EDGES;
    int n = min(T_EDGES, E - base);

    int chunk = (NB + 1023) / 1024;
    int lo = t * chunk, hi = min(lo + chunk, NB);
    int s = 0;
    for (int i = lo; i < hi; i++) {
        int c = ghist[(size_t)tb * NB + i];
        loff[i] = c;
        s += c;
    }
    part[t] = s;
    __syncthreads();
    for (int off = 1; off < 1024; off <<= 1) {
        int x = (t >= off) ? part[t - off] : 0;
        __syncthreads();
        part[t] += x;
        __syncthreads();
    }
    int run = part[t] - s;
    for (int i = lo; i < hi; i++) {
        int c = loff[i];
        loff[i] = run;
        lcur[i] = run;
        run += c;
    }
    __syncthreads();

    // rank: perm = local_idx | bucket<<14 | localdst<<25  (idx<6400 fits 14b)
    for (int i = t; i < n; i += 1024) {
        int d = dst[base + i];
        unsigned b = ((unsigned)d) >> 6;
        int p = atomicAdd(&lcur[b], 1);
        perm[p] = (unsigned)i | (b << 14) | ((unsigned)(d & 63) << 25);
    }
    __syncthreads();

    for (int o = t; o < n; o += 1024) {
        unsigned v = perm[o];
        int li = v & 16383;
        int b  = (v >> 14) & 2047;
        int ld = v >> 25;
        int g  = goff[(size_t)tb * NB + b] + (o - loff[b]);
        edges[g] = make_int2(src[base + li] | (ld << 17), __float_as_int(val[base + li]));
    }
}

// ---- finalize: per-bucket LDS reorder, sort by local dst (enables run-accum) ----
// 1024 threads: 41.7 KB LDS -> 2 blocks/CU x 16 waves = 32 waves/CU
__global__ __launch_bounds__(1024) void finalize_kernel(int2* __restrict__ edges,
                                                        const int* __restrict__ btot) {
    __shared__ int2 recs[FCAP];          // 20480 B
    __shared__ int2 recs2[FCAP];         // 20480 B
    __shared__ int cnt[64], offs[64], cur[64];
    int b = blockIdx.x, t = threadIdx.x;
    size_t s0 = (size_t)b * FCAP;
    int ne = min(btot[b], FCAP);
    if (t < 64) cnt[t] = 0;
    __syncthreads();
    for (int i = t; i < ne; i += 1024) {
        int2 r = edges[s0 + i];
        recs[i] = r;
        atomicAdd(&cnt[(r.x >> 17) & 63], 1);
    }
    __syncthreads();
    if (t == 0) {
        int run = 0;
        for (int i = 0; i < 64; i++) { offs[i] = run; run += cnt[i]; }
    }
    __syncthreads();
    if (t < 64) cur[t] = offs[t];
    __syncthreads();
    for (int i = t; i < ne; i += 1024) {
        int2 r = recs[i];
        int ld = (r.x >> 17) & 63;
        int p = atomicAdd(&cur[ld], 1);
        recs2[p] = r;                         // keep ld packed for gather
    }
    __syncthreads();
    for (int i = t; i < ne; i += 1024) edges[s0 + i] = recs2[i];  // coalesced
}

// ---- bucket-parallel fused layer (R6's proven body):
//   agg_k (staged ebuf, run-accumulated) + h=act(agg+b_k) + s_{k+1}=h@W_{k+1}
// SV: float4-stride of input rows. NACC: float4s accumulated (<=SV).
// ACT: 0 none, 1 relu, 2 tanhshrink.  FINAL: write h as DIN floats.
template <int SV, int NACC, int DIN, int DOUT, int OSTR, int ACT, bool FINAL>
__global__ __launch_bounds__(256) void layer_kernel(const int2* __restrict__ edges,
                                                    const int* __restrict__ btot,
                                                    const float* __restrict__ s,
                                                    const float* __restrict__ bias,
                                                    const float* __restrict__ W,
                                                    float* __restrict__ out, int N) {
    constexpr int ASTR = 13;                 // padded acc stride (conflict-free)
    __shared__ int2  ebuf[FCAP];             // 20480 B
    __shared__ float acc[64 * ASTR];         // 3328 B
    const int b = blockIdx.x, t = threadIdx.x;
    const int ne = min(btot[b], FCAP);

    for (int i = t; i < 64 * ASTR; i += 256) acc[i] = 0.f;
    // stage: int4 = 2 edges per lane-op (FCAP even; over-read <=1 int2, in-bounds)
    {
        const int4* esrc = (const int4*)(edges + (size_t)b * FCAP);
        int4*       edst = (int4*)ebuf;
        const int nq = (ne + 1) >> 1;
        for (int i = t; i < nq; i += 256) edst[i] = esrc[i];
    }
    __syncthreads();

    // per-thread contiguous chunk of sorted edges; run-accumulate in registers
    const int K  = (ne + 255) >> 8;          // <= 10
    const int i0 = t * K;
    const int i1 = min(i0 + K, ne);
    if (i0 < i1) {
        const float4* sv = (const float4*)s;
        float4 a[NACC];
#pragma unroll
        for (int v = 0; v < NACC; v++) a[v] = make_float4(0.f, 0.f, 0.f, 0.f);
        int cd = (ebuf[i0].x >> 17) & 63;
        for (int i = i0; i < i1; ++i) {
            int2 ev = ebuf[i];
            int ld = (ev.x >> 17) & 63;
            if (ld != cd) {
#pragma unroll
                for (int v = 0; v < NACC; v++) {
                    atomicAdd(&acc[cd * ASTR + 4 * v + 0], a[v].x);
                    atomicAdd(&acc[cd * ASTR + 4 * v + 1], a[v].y);
                    atomicAdd(&acc[cd * ASTR + 4 * v + 2], a[v].z);
                    atomicAdd(&acc[cd * ASTR + 4 * v + 3], a[v].w);
                    a[v] = make_float4(0.f, 0.f, 0.f, 0.f);
                }
                cd = ld;
            }
            float w = __int_as_float(ev.y);
            const float4* srow = sv + (size_t)(ev.x & 0x1FFFF) * SV;
#pragma unroll
            for (int v = 0; v < NACC; v++) {
                float4 xr = srow[v];
                a[v].x += w * xr.x; a[v].y += w * xr.y;
                a[v].z += w * xr.z; a[v].w += w * xr.w;
            }
        }
#pragma unroll
        for (int v = 0; v < NACC; v++) {
            atomicAdd(&acc[cd * ASTR + 4 * v + 0], a[v].x);
            atomicAdd(&acc[cd * ASTR + 4 * v + 1], a[v].y);
            atomicAdd(&acc[cd * ASTR + 4 * v + 2], a[v].z);
            atomicAdd(&acc[cd * ASTR + 4 * v + 3], a[v].w);
        }
    }
    __syncthreads();

    // epilogue: node-per-thread (t<64), bias+act, next dense, coalesced store
    if (t < 64) {
        int node = (b << 6) + t;
        if (node < N) {
            float h[DIN];
#pragma unroll
            for (int k = 0; k < DIN; k++) {
                float z = acc[t * ASTR + k] + bias[k];
                if (ACT == 1) z = fmaxf(z, 0.f);
                else if (ACT == 2) z = z - tanhf(z);
                h[k] = z;
            }
            if (FINAL) {
#pragma unroll
                for (int k = 0; k < DIN; k++) out[(size_t)node * DIN + k] = h[k];
            } else {
                float o[OSTR];
#pragma unroll
                for (int j = 0; j < OSTR; j++) o[j] = 0.f;  // zero pads
#pragma unroll
                for (int j = 0; j < DOUT; j++) {
                    float tj = 0.f;
#pragma unroll
                    for (int k = 0; k < DIN; k++) tj += h[k] * W[k * DOUT + j];
                    o[j] = tj;
                }
                float4* orow = (float4*)(out + (size_t)node * OSTR);
#pragma unroll
                for (int v = 0; v < OSTR / 4; v++)
                    orow[v] = make_float4(o[4 * v], o[4 * v + 1], o[4 * v + 2], o[4 * v + 3]);
            }
        }
    }
}

// ---------------- launcher ----------------

static inline size_t align256(size_t x) { return (x + 255) & ~(size_t)255; }

extern "C" void kernel_launch(void* const* d_in, const int* in_sizes, int n_in,
                              void* d_out, int out_size, void* d_ws, size_t ws_size,
                              hipStream_t stream) {
    const float* x        = (const float*)d_in[0];
    const float* edge_val = (const float*)d_in[1];
    const int*   edge_src = (const int*)d_in[2];
    const int*   edge_dst = (const int*)d_in[3];
    const float* W1 = (const float*)d_in[4];   const float* b1 = (const float*)d_in[5];
    const float* W2 = (const float*)d_in[6];   const float* b2 = (const float*)d_in[7];
    const float* W3 = (const float*)d_in[8];   const float* b3 = (const float*)d_in[9];
    const float* W4 = (const float*)d_in[10];  const float* b4 = (const float*)d_in[11];
    const float* W5 = (const float*)d_in[12];  const float* b5 = (const float*)d_in[13];
    const float* W6 = (const float*)d_in[14];  const float* b6 = (const float*)d_in[15];

    const int N = in_sizes[0] / 512;        // 100000
    const int E = in_sizes[1];              // 3200000
    float* out = (float*)d_out;

    const int NB = (N + 63) >> 6;           // 1563 fine buckets
    const int NT = (E + T_EDGES - 1) / T_EDGES;  // 500 tiles (<=512 for scanC)
    const int nb = (N + 255) / 256;         // 391 dense1 blocks

    // workspace carve-up (~63 MB)
    char* w = (char*)d_ws;
    float* A     = (float*)w;  w += align256((size_t)N * 16 * sizeof(float));
    float* B     = (float*)w;  w += align256((size_t)N * 16 * sizeof(float));
    int*   ghist = (int*)w;    w += align256((size_t)NT * NB * sizeof(int));
    int*   goff  = (int*)w;    w += align256((size_t)NT * NB * sizeof(int));
    int*   btot  = (int*)w;    w += align256((size_t)NB * sizeof(int));
    int2*  edges = (int2*)w;   w += align256((size_t)NB * FCAP * sizeof(int2));

    // ---- fused hist + dense1 (hist hides under dense1's 204 MB stream) ----
    hist_dense1_kernel<<<NT + nb, 256, 0, stream>>>(edge_dst, ghist, x, W1, A, E, NB, NT, N);

    // ---- CSR build: padded bucket layout + ld-sort ----
    scanC_kernel<<<NB, 512, 0, stream>>>(ghist, goff, btot, NT, NB);
    scatter_kernel<<<NT, 1024, 0, stream>>>(edge_src, edge_dst, edge_val, ghist, goff, edges, E, NB);
    finalize_kernel<<<NB, 1024, 0, stream>>>(edges, btot);

    // ---- fused bucket-parallel gather+dense chain (R6 bodies) ----
    // G1: agg(s1,str16) -> h1=agg+b1 -> s2=h1@W2 (12->10, out stride 16)
    layer_kernel<4, 3, 12, 10, 16, 0, false><<<NB, 256, 0, stream>>>(edges, btot, A, b1, W2, B, N);
    // G2: agg(s2,str16) -> h2=relu -> s3=h2@W3 (10->8, out stride 8)
    layer_kernel<4, 3, 10, 8, 8, 1, false><<<NB, 256, 0, stream>>>(edges, btot, B, b2, W3, A, N);
    // G3: agg(s3,str8) -> h3=ts -> s4=h3@W4 (8->6, out stride 8)
    layer_kernel<2, 2, 8, 6, 8, 2, false><<<NB, 256, 0, stream>>>(edges, btot, A, b3, W4, B, N);
    // G4: agg(s4,str8) -> h4=ts -> s5=h4@W5 (6->4, out stride 4)
    layer_kernel<2, 2, 6, 4, 4, 2, false><<<NB, 256, 0, stream>>>(edges, btot, B, b4, W5, A, N);
    // G5: agg(s5,str4) -> h5=agg+b5 -> s6=h5@W6 (4->7, out stride 8)
    layer_kernel<1, 1, 4, 7, 8, 0, false><<<NB, 256, 0, stream>>>(edges, btot, A, b5, W6, B, N);
    // G6: out = agg6 + b6 (7 floats, exact layout)
    layer_kernel<2, 2, 7, 7, 8, 0, true><<<NB, 256, 0, stream>>>(edges, btot, B, b6, (const float*)nullptr, out, N);
}